// Round 5
// baseline (684.269 us; speedup 1.0000x reference)
//
#include <hip/hip_runtime.h>
#include <hip/hip_bf16.h>

// B=2 H=16 S=2048 D=64, causal. Output = context (B,H,S,D) ++ attention (B,H,S,S), fp32.
// Pair-fused blocks: block (pi,bh) processes q-tiles lo=pi and hi=31-pi in ONE K/V sweep
// (tiles 0..hi). Uniform work: 33x16 MFMA and 64x1984 zero-fill per block, all blocks.

constexpr int SEQ = 2048;
constexpr int HD  = 64;
constexpr int NHEADS = 32;   // B*H
constexpr int QT  = 64;      // tile rows
constexpr int NT  = SEQ / QT;

typedef __bf16 bf16x8 __attribute__((ext_vector_type(8)));
typedef unsigned short u16x8 __attribute__((ext_vector_type(8)));
typedef unsigned short u16x4 __attribute__((ext_vector_type(4)));
typedef float f32x4 __attribute__((ext_vector_type(4)));
typedef unsigned short us;

__device__ __forceinline__ us f2bf(float x) {
  unsigned u = __builtin_bit_cast(unsigned, x);
  return (us)((u + 0x7fffu + ((u >> 16) & 1u)) >> 16);  // RNE
}
__device__ __forceinline__ float bf2f(us b) {
  return __builtin_bit_cast(float, (unsigned)b << 16);
}

__launch_bounds__(256, 4)
__global__ void attn_kernel(const float* __restrict__ Qg,
                            const float* __restrict__ Kg,
                            const float* __restrict__ Vg,
                            float* __restrict__ out) {
  const int fb = blockIdx.x;                 // 0..511, XCD-friendly decode
  const int bh = (fb >> 1) & (NHEADS - 1);   // same-head blocks share 2 XCD classes
  const int pi = (fb & 1) + 2 * (fb >> 6);   // 0..15
  const int t  = threadIdx.x;
  const int l  = t & 63;
  const int w  = t >> 6;        // wave 0..3, owns q-rows w*16..w*16+15 of BOTH tiles
  const int l16 = l & 15;
  const int lg  = l >> 4;       // 0..3

  const int lo = pi, hi = NT - 1 - pi;
  const int nkt = hi + 1;       // K/V tiles 0..hi

  __shared__ __align__(16) us Qs[2][QT * HD];  // lo, hi (b128-read swizzle)
  __shared__ __align__(16) us Ks[QT * HD];     // b128-read swizzle
  __shared__ __align__(16) us Vs[QT * HD];     // [key][d], u16-gather swizzle
  __shared__ __align__(16) us Ps[4][16 * QT];  // per-wave strip, reused hi/lo

  const size_t hoff = (size_t)bh * SEQ * HD;
  const float* Qh = Qg + hoff;
  const float* Kh = Kg + hoff;
  const float* Vh = Vg + hoff;
  float* ctx = out + hoff;
  float* att = out + (size_t)NHEADS * SEQ * HD + (size_t)bh * SEQ * SEQ;

  auto load_tile = [&](const float* src, f32x4 (&reg)[4]) {
    #pragma unroll
    for (int j = 0; j < 4; ++j) {
      const int f = t + 256 * j;
      reg[j] = *(const f32x4*)(src + (size_t)(f >> 4) * HD + 4 * (f & 15));
    }
  };
  auto write_k = [&](const f32x4 (&reg)[4], us* dst) {
    #pragma unroll
    for (int j = 0; j < 4; ++j) {
      const int f = t + 256 * j;
      const int r = f >> 4, c4 = f & 15;
      const int idx = (r * 64 + 4 * c4) ^ ((r & 7) << 3);
      u16x4 b = { f2bf(reg[j].x), f2bf(reg[j].y), f2bf(reg[j].z), f2bf(reg[j].w) };
      *(u16x4*)(&dst[idx]) = b;
    }
  };
  auto write_vv = [&](const f32x4 (&reg)[4], us* dst) {
    #pragma unroll
    for (int j = 0; j < 4; ++j) {
      const int f = t + 256 * j;
      const int r = f >> 4, c4 = f & 15;
      const int idx = (r * 64 + 4 * c4) ^ (((r >> 3) & 3) << 4);
      u16x4 b = { f2bf(reg[j].x), f2bf(reg[j].y), f2bf(reg[j].z), f2bf(reg[j].w) };
      *(u16x4*)(&dst[idx]) = b;
    }
  };

  const float sc = 0.125f;  // 1/sqrt(64)
  const int qg_lo = lo * QT + w * 16 + l16;
  const int qg_hi = hi * QT + w * 16 + l16;

  // ---- zero-fill masked columns for both tiles (nt, full-line) ----
  {
    auto zfill = [&](int qb, int zc0) {
      const int nz4 = (SEQ - zc0) >> 2;
      for (int r = 0; r < QT; ++r) {
        float* rowp = att + (size_t)(qb + r) * SEQ + zc0;
        for (int c = t; c < nz4; c += 256)
          __builtin_nontemporal_store((f32x4){0.f, 0.f, 0.f, 0.f}, (f32x4*)(rowp + 4 * c));
      }
    };
    zfill(lo * QT, (lo + 1) * QT);
    zfill(hi * QT, (hi + 1) * QT);
  }

  // ---- stage both Q tiles; preload Q B-fragments ----
  {
    f32x4 q0[4], q1[4];
    load_tile(Qh + (size_t)lo * QT * HD, q0);
    load_tile(Qh + (size_t)hi * QT * HD, q1);
    write_k(q0, Qs[0]);
    write_k(q1, Qs[1]);
  }
  __syncthreads();

  bf16x8 aql[2], aqh[2];
  #pragma unroll
  for (int ks = 0; ks < 2; ++ks) {
    const int qr = w * 16 + l16;
    const int d0 = ks * 32 + lg * 8;
    const int idx = (qr * 64 + d0) ^ ((qr & 7) << 3);
    aql[ks] = __builtin_bit_cast(bf16x8, *(const u16x8*)(&Qs[0][idx]));
    aqh[ks] = __builtin_bit_cast(bf16x8, *(const u16x8*)(&Qs[1][idx]));
  }

  // ================= phase 1: row sums for both tiles =================
  float rs_lo = 0.f, rs_hi = 0.f;
  {
    f32x4 kreg[4];
    load_tile(Kh, kreg);
    write_k(kreg, Ks);
    __syncthreads();
    for (int kt = 0; kt < nkt; ++kt) {
      if (kt + 1 < nkt) load_tile(Kh + (size_t)(kt + 1) * QT * HD, kreg);
      const int kb_ = kt * QT;
      const bool loact = (kt <= pi);
      #pragma unroll
      for (int ct = 0; ct < 4; ++ct) {
        f32x4 acch = {0.f, 0.f, 0.f, 0.f};
        f32x4 accl = {0.f, 0.f, 0.f, 0.f};
        #pragma unroll
        for (int ks = 0; ks < 2; ++ks) {
          const int kr = ct * 16 + l16;
          const int d0 = ks * 32 + lg * 8;
          const int idx = (kr * 64 + d0) ^ ((kr & 7) << 3);
          bf16x8 bk = __builtin_bit_cast(bf16x8, *(const u16x8*)(&Ks[idx]));
          acch = __builtin_amdgcn_mfma_f32_16x16x32_bf16(bk, aqh[ks], acch, 0, 0, 0);
          if (loact)
            accl = __builtin_amdgcn_mfma_f32_16x16x32_bf16(bk, aql[ks], accl, 0, 0, 0);
        }
        const int kg0 = kb_ + ct * 16 + lg * 4;
        #pragma unroll
        for (int r = 0; r < 4; ++r)
          rs_hi += (kg0 + r <= qg_hi) ? __expf(acch[r] * sc) : 0.f;
        if (loact) {
          #pragma unroll
          for (int r = 0; r < 4; ++r)
            rs_lo += (kg0 + r <= qg_lo) ? __expf(accl[r] * sc) : 0.f;
        }
      }
      __syncthreads();
      if (kt + 1 < nkt) write_k(kreg, Ks);
      __syncthreads();
    }
  }
  rs_lo += __shfl_xor(rs_lo, 16);
  rs_lo += __shfl_xor(rs_lo, 32);
  rs_hi += __shfl_xor(rs_hi, 16);
  rs_hi += __shfl_xor(rs_hi, 32);
  const float inv_lo = 1.f / rs_lo;
  const float inv_hi = 1.f / rs_hi;

  // ================= phase 2: P -> att + O = P·V, both tiles =================
  f32x4 oacc_lo[4], oacc_hi[4];
  #pragma unroll
  for (int ct = 0; ct < 4; ++ct) {
    oacc_lo[ct] = (f32x4){0.f, 0.f, 0.f, 0.f};
    oacc_hi[ct] = (f32x4){0.f, 0.f, 0.f, 0.f};
  }

  // one q-tile's P/att/PV for the current staged K/V tile (all args compile-time refs)
  auto do_tile = [&](const bf16x8 (&aq)[2], int qg, float inv, int qb,
                     f32x4 (&oa)[4], int kb_) {
    #pragma unroll
    for (int ct = 0; ct < 4; ++ct) {
      f32x4 acc = {0.f, 0.f, 0.f, 0.f};
      #pragma unroll
      for (int ks = 0; ks < 2; ++ks) {
        const int kr = ct * 16 + l16;
        const int d0 = ks * 32 + lg * 8;
        const int idx = (kr * 64 + d0) ^ ((kr & 7) << 3);
        bf16x8 bk = __builtin_bit_cast(bf16x8, *(const u16x8*)(&Ks[idx]));
        acc = __builtin_amdgcn_mfma_f32_16x16x32_bf16(bk, aq[ks], acc, 0, 0, 0);
      }
      const int kg0 = kb_ + ct * 16 + lg * 4;
      u16x4 pb;
      #pragma unroll
      for (int r = 0; r < 4; ++r) {
        float e = __expf(acc[r] * sc) * inv;
        pb[r] = f2bf((kg0 + r <= qg) ? e : 0.f);
      }
      const int pidx = (l16 * 64 + ct * 16 + lg * 4) ^ ((l16 & 7) << 3);
      *(u16x4*)(&Ps[w][pidx]) = pb;
    }
    // att copy: own-wave rows, 256B/row contiguous, nontemporal
    #pragma unroll
    for (int j = 0; j < 4; ++j) {
      const int rloc = lg + 4 * j;
      const int idx = (rloc * 64 + 4 * l16) ^ ((rloc & 7) << 3);
      u16x4 p4 = *(const u16x4*)(&Ps[w][idx]);
      f32x4 pv = { bf2f(p4[0]), bf2f(p4[1]), bf2f(p4[2]), bf2f(p4[3]) };
      __builtin_nontemporal_store(pv,
          (f32x4*)(att + (size_t)(qb + w * 16 + rloc) * SEQ + kb_ + 4 * l16));
    }
    // PV: A = V^T (u16 gather, swizzled), B = P^T (own-wave strip)
    #pragma unroll
    for (int ct = 0; ct < 4; ++ct) {
      #pragma unroll
      for (int ks = 0; ks < 2; ++ks) {
        const int key0 = ks * 32 + lg * 8;
        const int pidx = (l16 * 64 + key0) ^ ((l16 & 7) << 3);
        bf16x8 pa = __builtin_bit_cast(bf16x8, *(const u16x8*)(&Ps[w][pidx]));
        bf16x8 av;
        const int dcol = ct * 16 + l16;
        const int xorv = ((key0 >> 3) & 3) << 4;
        #pragma unroll
        for (int jj = 0; jj < 8; ++jj)
          av[jj] = __builtin_bit_cast(__bf16, Vs[((key0 + jj) * 64 + dcol) ^ xorv]);
        oa[ct] = __builtin_amdgcn_mfma_f32_16x16x32_bf16(av, pa, oa[ct], 0, 0, 0);
      }
    }
  };

  {
    f32x4 kreg[4], vreg[4];
    load_tile(Kh, kreg);
    load_tile(Vh, vreg);
    write_k(kreg, Ks);
    write_vv(vreg, Vs);
    __syncthreads();
    for (int kt = 0; kt < nkt; ++kt) {
      if (kt + 1 < nkt) {
        load_tile(Kh + (size_t)(kt + 1) * QT * HD, kreg);
        load_tile(Vh + (size_t)(kt + 1) * QT * HD, vreg);
      }
      const int kb_ = kt * QT;
      do_tile(aqh, qg_hi, inv_hi, hi * QT, oacc_hi, kb_);
      if (kt <= pi)
        do_tile(aql, qg_lo, inv_lo, lo * QT, oacc_lo, kb_);
      __syncthreads();
      if (kt + 1 < nkt) {
        write_k(kreg, Ks);
        write_vv(vreg, Vs);
      }
      __syncthreads();
    }
  }

  // ---- write context for both tiles (nt dwordx4) ----
  #pragma unroll
  for (int ct = 0; ct < 4; ++ct) {
    __builtin_nontemporal_store(oacc_lo[ct],
        (f32x4*)(ctx + (size_t)qg_lo * HD + ct * 16 + lg * 4));
    __builtin_nontemporal_store(oacc_hi[ct],
        (f32x4*)(ctx + (size_t)qg_hi * HD + ct * 16 + lg * 4));
  }
}

extern "C" void kernel_launch(void* const* d_in, const int* in_sizes, int n_in,
                              void* d_out, int out_size, void* d_ws, size_t ws_size,
                              hipStream_t stream) {
  const float* Q = (const float*)d_in[0];
  const float* K = (const float*)d_in[1];
  const float* V = (const float*)d_in[2];
  float* out = (float*)d_out;
  attn_kernel<<<dim3(NT / 2 * NHEADS), dim3(256), 0, stream>>>(Q, K, V, out);
}

// Round 6
// 153.345 us; speedup vs baseline: 4.4623x; 4.4623x over previous
//
#include <hip/hip_runtime.h>
#include <hip/hip_bf16.h>

// B=2 H=16 S=2048 D=64, causal. Output = context (B,H,S,D) ++ attention (B,H,S,S), fp32.
// R3 structure (uniform-work pair blocks, two-pass softmax) + XCD-pinned heads:
// fb = pi*32 + bh  =>  all 16 blocks of head bh share fb%8 == bh%8  => one XCD's L2
// holds that head's K/V (1 MB); 4 heads/XCD = 4 MB = L2 size. nt stores don't thrash it.

constexpr int SEQ = 2048;
constexpr int HD  = 64;
constexpr int NHEADS = 32;   // B*H
constexpr int QT  = 64;      // q-tile rows (also k-tile width)
constexpr int NT  = SEQ / QT;

typedef __bf16 bf16x8 __attribute__((ext_vector_type(8)));
typedef unsigned short u16x8 __attribute__((ext_vector_type(8)));
typedef unsigned short u16x4 __attribute__((ext_vector_type(4)));
typedef float f32x4 __attribute__((ext_vector_type(4)));
typedef unsigned short us;

__device__ __forceinline__ us f2bf(float x) {
  unsigned u = __builtin_bit_cast(unsigned, x);
  return (us)((u + 0x7fffu + ((u >> 16) & 1u)) >> 16);  // RNE
}
__device__ __forceinline__ float bf2f(us b) {
  return __builtin_bit_cast(float, (unsigned)b << 16);
}

__launch_bounds__(256, 2)
__global__ void attn_kernel(const float* __restrict__ Qg,
                            const float* __restrict__ Kg,
                            const float* __restrict__ Vg,
                            float* __restrict__ out) {
  const int fb = blockIdx.x;
  const int bh = fb & (NHEADS - 1);   // head; fb%8 == bh%8 -> fixed XCD under round-robin
  const int pi = fb >> 5;             // 0..15 : pair index
  const int t  = threadIdx.x;
  const int l  = t & 63;
  const int w  = t >> 6;        // wave 0..3, owns q-rows w*16..w*16+15
  const int l16 = l & 15;
  const int lg  = l >> 4;       // 0..3

  __shared__ __align__(16) us Qs[QT * HD];
  __shared__ __align__(16) us Ks[QT * HD];     // b128-read swizzle
  __shared__ __align__(16) us Vs[QT * HD];     // [key][d], u16-gather swizzle
  __shared__ __align__(16) us Ps[4][16 * QT];  // per-wave P strip [q=16][k=64]

  const size_t hoff = (size_t)bh * SEQ * HD;
  const float* Qh = Qg + hoff;
  const float* Kh = Kg + hoff;
  const float* Vh = Vg + hoff;
  float* ctx = out + hoff;
  float* att = out + (size_t)NHEADS * SEQ * HD + (size_t)bh * SEQ * SEQ;

  auto load_tile = [&](const float* src, f32x4 (&reg)[4]) {
    #pragma unroll
    for (int j = 0; j < 4; ++j) {
      const int f = t + 256 * j;
      reg[j] = *(const f32x4*)(src + (size_t)(f >> 4) * HD + 4 * (f & 15));
    }
  };
  auto write_k = [&](const f32x4 (&reg)[4], us* dst) {
    #pragma unroll
    for (int j = 0; j < 4; ++j) {
      const int f = t + 256 * j;
      const int r = f >> 4, c4 = f & 15;
      const int idx = (r * 64 + 4 * c4) ^ ((r & 7) << 3);
      u16x4 b = { f2bf(reg[j].x), f2bf(reg[j].y), f2bf(reg[j].z), f2bf(reg[j].w) };
      *(u16x4*)(&dst[idx]) = b;
    }
  };
  auto write_vv = [&](const f32x4 (&reg)[4], us* dst) {
    #pragma unroll
    for (int j = 0; j < 4; ++j) {
      const int f = t + 256 * j;
      const int r = f >> 4, c4 = f & 15;
      const int idx = (r * 64 + 4 * c4) ^ (((r >> 3) & 3) << 4);
      u16x4 b = { f2bf(reg[j].x), f2bf(reg[j].y), f2bf(reg[j].z), f2bf(reg[j].w) };
      *(u16x4*)(&dst[idx]) = b;
    }
  };

  const float sc = 0.125f;  // 1/sqrt(64)

  for (int half = 0; half < 2; ++half) {
    const int qt = half ? (NT - 1 - pi) : pi;
    const int qbase = qt * QT;
    const int qg = qbase + w * 16 + l16;   // this lane's q-row (S^T layout)

    __syncthreads();   // between halves

    // ---- zero-fill masked columns (nontemporal, full-line coalesced) ----
    {
      const int zc0 = (qt + 1) * QT;
      const int nz4 = (SEQ - zc0) >> 2;
      for (int r = 0; r < QT; ++r) {
        float* rowp = att + (size_t)(qbase + r) * SEQ + zc0;
        for (int c = t; c < nz4; c += 256)
          __builtin_nontemporal_store((f32x4){0.f, 0.f, 0.f, 0.f}, (f32x4*)(rowp + 4 * c));
      }
    }

    // ---- stage Q; preload Q B-fragments ----
    {
      f32x4 qreg[4];
      load_tile(Qh + (size_t)qbase * HD, qreg);
      write_k(qreg, Qs);
    }
    __syncthreads();

    bf16x8 aq[2];
    #pragma unroll
    for (int ks = 0; ks < 2; ++ks) {
      const int qr = w * 16 + l16;
      const int d0 = ks * 32 + lg * 8;
      const int idx = (qr * 64 + d0) ^ ((qr & 7) << 3);
      aq[ks] = __builtin_bit_cast(bf16x8, *(const u16x8*)(&Qs[idx]));
    }

    // ================= phase 1: row sums of exp(scores) =================
    float rsum = 0.f;
    {
      f32x4 kreg[4];
      load_tile(Kh, kreg);
      write_k(kreg, Ks);
      __syncthreads();
      for (int kt = 0; kt <= qt; ++kt) {
        if (kt < qt) load_tile(Kh + (size_t)(kt + 1) * QT * HD, kreg);  // prefetch
        const int kb = kt * QT;
        #pragma unroll
        for (int ct = 0; ct < 4; ++ct) {
          f32x4 acc = {0.f, 0.f, 0.f, 0.f};
          #pragma unroll
          for (int ks = 0; ks < 2; ++ks) {
            const int kr = ct * 16 + l16;
            const int d0 = ks * 32 + lg * 8;
            const int idx = (kr * 64 + d0) ^ ((kr & 7) << 3);
            bf16x8 bk = __builtin_bit_cast(bf16x8, *(const u16x8*)(&Ks[idx]));
            acc = __builtin_amdgcn_mfma_f32_16x16x32_bf16(bk, aq[ks], acc, 0, 0, 0);  // S^T
          }
          const int kg0 = kb + ct * 16 + lg * 4;
          #pragma unroll
          for (int r = 0; r < 4; ++r) {
            float e = __expf(acc[r] * sc);
            rsum += (kg0 + r <= qg) ? e : 0.f;
          }
        }
        __syncthreads();
        if (kt < qt) write_k(kreg, Ks);
        __syncthreads();
      }
    }
    rsum += __shfl_xor(rsum, 16);
    rsum += __shfl_xor(rsum, 32);
    const float inv = 1.f / rsum;

    // ================= phase 2: P -> att + O = P·V =================
    f32x4 oacc[4];
    #pragma unroll
    for (int ct = 0; ct < 4; ++ct) oacc[ct] = (f32x4){0.f, 0.f, 0.f, 0.f};

    {
      f32x4 kreg[4], vreg[4];
      load_tile(Kh, kreg);
      load_tile(Vh, vreg);
      write_k(kreg, Ks);
      write_vv(vreg, Vs);
      __syncthreads();
      for (int kt = 0; kt <= qt; ++kt) {
        if (kt < qt) {
          load_tile(Kh + (size_t)(kt + 1) * QT * HD, kreg);  // prefetch
          load_tile(Vh + (size_t)(kt + 1) * QT * HD, vreg);
        }
        const int kb = kt * QT;

        // QK^T (swapped) -> normalized bf16 P into Ps
        #pragma unroll
        for (int ct = 0; ct < 4; ++ct) {
          f32x4 acc = {0.f, 0.f, 0.f, 0.f};
          #pragma unroll
          for (int ks = 0; ks < 2; ++ks) {
            const int kr = ct * 16 + l16;
            const int d0 = ks * 32 + lg * 8;
            const int idx = (kr * 64 + d0) ^ ((kr & 7) << 3);
            bf16x8 bk = __builtin_bit_cast(bf16x8, *(const u16x8*)(&Ks[idx]));
            acc = __builtin_amdgcn_mfma_f32_16x16x32_bf16(bk, aq[ks], acc, 0, 0, 0);
          }
          const int kg0 = kb + ct * 16 + lg * 4;
          u16x4 pb;
          #pragma unroll
          for (int r = 0; r < 4; ++r) {
            float e = __expf(acc[r] * sc) * inv;
            pb[r] = f2bf((kg0 + r <= qg) ? e : 0.f);
          }
          const int pidx = (l16 * 64 + ct * 16 + lg * 4) ^ ((l16 & 7) << 3);
          *(u16x4*)(&Ps[w][pidx]) = pb;
        }

        // PV (swapped): A = V^T (per-element gather), B = P^T strip (wave-local)
        #pragma unroll
        for (int ct = 0; ct < 4; ++ct) {
          #pragma unroll
          for (int ks = 0; ks < 2; ++ks) {
            const int key0 = ks * 32 + lg * 8;
            const int pidx = (l16 * 64 + key0) ^ ((l16 & 7) << 3);
            bf16x8 pa = __builtin_bit_cast(bf16x8, *(const u16x8*)(&Ps[w][pidx]));
            bf16x8 av;
            const int dcol = ct * 16 + l16;
            const int xorv = ((key0 >> 3) & 3) << 4;
            #pragma unroll
            for (int j = 0; j < 8; ++j) {
              av[j] = __builtin_bit_cast(__bf16, Vs[((key0 + j) * 64 + dcol) ^ xorv]);
            }
            oacc[ct] = __builtin_amdgcn_mfma_f32_16x16x32_bf16(av, pa, oacc[ct], 0, 0, 0);
          }
        }

        __syncthreads();   // Ps complete; Ks/Vs reads retired

        // att copy: full-line coalesced nontemporal stores (4 rows/wave, 256B/row)
        #pragma unroll
        for (int j = 0; j < 4; ++j) {
          const int f = t + 256 * j;
          const int r = f >> 4, c4 = f & 15;
          const int ww = r >> 4, qr = r & 15;
          const int idx = (qr * 64 + 4 * c4) ^ ((qr & 7) << 3);
          u16x4 pb = *(const u16x4*)(&Ps[ww][idx]);
          f32x4 pv = { bf2f(pb[0]), bf2f(pb[1]), bf2f(pb[2]), bf2f(pb[3]) };
          __builtin_nontemporal_store(pv,
              (f32x4*)(att + (size_t)(qbase + r) * SEQ + kb + 4 * c4));
        }

        if (kt < qt) {        // overwrite Ks/Vs for next iter (disjoint from Ps)
          write_k(kreg, Ks);
          write_vv(vreg, Vs);
        }
        __syncthreads();
      }
    }

    // ---- write context: O[q=l16][d = ct*16 + lg*4 + r] -> dwordx4 ----
    #pragma unroll
    for (int ct = 0; ct < 4; ++ct) {
      *(f32x4*)(ctx + (size_t)qg * HD + ct * 16 + lg * 4) = oacc[ct];
    }
  }
}

extern "C" void kernel_launch(void* const* d_in, const int* in_sizes, int n_in,
                              void* d_out, int out_size, void* d_ws, size_t ws_size,
                              hipStream_t stream) {
  const float* Q = (const float*)d_in[0];
  const float* K = (const float*)d_in[1];
  const float* V = (const float*)d_in[2];
  float* out = (float*)d_out;
  attn_kernel<<<dim3(NT / 2 * NHEADS), dim3(256), 0, stream>>>(Q, K, V, out);
}

// Round 7
// 142.053 us; speedup vs baseline: 4.8170x; 1.0795x over previous
//
#include <hip/hip_runtime.h>
#include <hip/hip_bf16.h>

// B=2 H=16 S=2048 D=64, causal. Output = context (B,H,S,D) ++ attention (B,H,S,S), fp32.
// prep: fp32->bf16 pre-swizzled LDS images in d_ws (K/Q row-major swz, V transposed swz).
// main: R6 skeleton + global_load_lds(16B) dbuf staging, b128 PV reads, 1 barrier/iter.

constexpr int SEQ = 2048;
constexpr int HD  = 64;
constexpr int NHEADS = 32;   // B*H
constexpr int QT  = 64;
constexpr int NT  = SEQ / QT;

typedef __bf16 bf16x8 __attribute__((ext_vector_type(8)));
typedef unsigned short u16x8 __attribute__((ext_vector_type(8)));
typedef unsigned short u16x4 __attribute__((ext_vector_type(4)));
typedef float f32x4 __attribute__((ext_vector_type(4)));
typedef unsigned short us;

__device__ __forceinline__ us f2bf(float x) {
  unsigned u = __builtin_bit_cast(unsigned, x);
  return (us)((u + 0x7fffu + ((u >> 16) & 1u)) >> 16);  // RNE
}
__device__ __forceinline__ float bf2f(us b) {
  return __builtin_bit_cast(float, (unsigned)b << 16);
}

#define GLOAD_LDS(gp, lp)                                                        \
  __builtin_amdgcn_global_load_lds(                                             \
      (const __attribute__((address_space(1))) void*)(gp),                      \
      (__attribute__((address_space(3))) void*)(lp), 16, 0, 0)

// stage one 8KB tile image -> LDS: 4 waves x 2 calls x 64 lanes x 16B
__device__ __forceinline__ void stage8k(const us* img, us* lds, int w, int l) {
  const char* g = (const char*)img + w * 2048 + l * 16;
  char* s = (char*)lds + w * 2048;
  GLOAD_LDS(g, s);
  GLOAD_LDS(g + 1024, s + 1024);
}

// ============ prep: build bf16 pre-swizzled tile images in scratch ============
// image elem (row r, col c) of Q/K tile at u16-idx (r*64+c) ^ ((r&7)<<3)
// image elem V^T (d, key)            at u16-idx (d*64+key) ^ ((d&7)<<3)
__global__ void prep_kernel(const float* __restrict__ Qg,
                            const float* __restrict__ Kg,
                            const float* __restrict__ Vg,
                            us* __restrict__ ws) {
  const int tile = blockIdx.x & (NT - 1);
  const int bh   = blockIdx.x >> 5;
  const int t = threadIdx.x;
  const size_t tOff = ((size_t)bh * SEQ + (size_t)tile * QT) * HD;
  us* Qi = ws + ((size_t)bh * NT + tile) * 4096;
  us* Ki = Qi + (size_t)NHEADS * NT * 4096;
  us* Vi = Ki + (size_t)NHEADS * NT * 4096;

  #pragma unroll
  for (int g0 = 0; g0 < 2; ++g0) {
    const int g = t + 256 * g0;          // 0..511 image chunks of 8 u16
    const int r = g >> 3, c8 = g & 7;
    const int cp = (8 * c8) ^ ((r & 7) << 3);   // source col for this chunk
    const float* qs = Qg + tOff + (size_t)r * HD + cp;
    const float* ks = Kg + tOff + (size_t)r * HD + cp;
    u16x8 q, k;
    #pragma unroll
    for (int j = 0; j < 8; ++j) { q[j] = f2bf(qs[j]); k[j] = f2bf(ks[j]); }
    *(u16x8*)(Qi + 8 * g) = q;
    *(u16x8*)(Ki + 8 * g) = k;
  }
  #pragma unroll
  for (int g0 = 0; g0 < 2; ++g0) {
    const int g = t + 256 * g0;
    const int d = g >> 3, k8 = g & 7;
    const int kp = (8 * k8) ^ ((d & 7) << 3);   // source key for this chunk
    const float* vs = Vg + tOff + d;
    u16x8 v;
    #pragma unroll
    for (int j = 0; j < 8; ++j) v[j] = f2bf(vs[(size_t)(kp + j) * HD]);
    *(u16x8*)(Vi + 8 * g) = v;
  }
}

// ======================= main attention kernel =======================
__launch_bounds__(256, 3)
__global__ void attn_main(const us* __restrict__ ws, float* __restrict__ out) {
  const int fb = blockIdx.x;
  const int bh = fb & (NHEADS - 1);   // fb%8==bh%8 -> head pinned to one XCD
  const int pi = fb >> 5;             // 0..15 pair index
  const int t  = threadIdx.x;
  const int l  = t & 63;
  const int w  = t >> 6;
  const int l16 = l & 15;
  const int lg  = l >> 4;

  __shared__ __align__(16) us Qs[4096];
  __shared__ __align__(16) us Ks[2][4096];
  __shared__ __align__(16) us Vs[2][4096];     // V^T images
  __shared__ __align__(16) us Ps[4][1024];     // per-wave P strip [q=16][k=64]

  const us* Qi = ws + (size_t)bh * NT * 4096;
  const us* Ki = Qi + (size_t)NHEADS * NT * 4096;
  const us* Vi = Ki + (size_t)NHEADS * NT * 4096;

  float* ctx = out + (size_t)bh * SEQ * HD;
  float* att = out + (size_t)NHEADS * SEQ * HD + (size_t)bh * SEQ * SEQ;

  const float KC = 0.18033688011112042f;  // (1/8) * log2(e)

  for (int half = 0; half < 2; ++half) {
    const int qt = half ? (NT - 1 - pi) : pi;
    const int qbase = qt * QT;
    const int qg = qbase + w * 16 + l16;     // lane's q-row (S^T: col=l16)

    // issue Q + first K stage, overlap with zero-fill stores, then one barrier
    stage8k(Qi + (size_t)qt * 4096, Qs, w, l);
    stage8k(Ki, Ks[0], w, l);
    {
      const int zc0 = (qt + 1) * QT;
      const int nz4 = (SEQ - zc0) >> 2;
      for (int r = 0; r < QT; ++r) {
        float* rowp = att + (size_t)(qbase + r) * SEQ + zc0;
        for (int c = t; c < nz4; c += 256)
          __builtin_nontemporal_store((f32x4){0.f, 0.f, 0.f, 0.f}, (f32x4*)(rowp + 4 * c));
      }
    }
    __syncthreads();

    bf16x8 aq[2];
    #pragma unroll
    for (int ks = 0; ks < 2; ++ks) {
      const int qr = w * 16 + l16;
      const int d0 = ks * 32 + lg * 8;
      const int idx = (qr * 64 + d0) ^ ((qr & 7) << 3);
      aq[ks] = __builtin_bit_cast(bf16x8, *(const u16x8*)(&Qs[idx]));
    }

    // ================= phase 1: row sums =================
    float rsum = 0.f;
    {
      int cur = 0;
      for (int kt = 0; kt <= qt; ++kt) {
        if (kt < qt) stage8k(Ki + (size_t)(kt + 1) * 4096, Ks[cur ^ 1], w, l);
        const us* krb = Ks[cur];
        const int kb = kt * QT;
        #pragma unroll
        for (int ct = 0; ct < 4; ++ct) {
          f32x4 acc = {0.f, 0.f, 0.f, 0.f};
          #pragma unroll
          for (int ks = 0; ks < 2; ++ks) {
            const int kr = ct * 16 + l16;
            const int d0 = ks * 32 + lg * 8;
            const int idx = (kr * 64 + d0) ^ ((kr & 7) << 3);
            bf16x8 bk = __builtin_bit_cast(bf16x8, *(const u16x8*)(&krb[idx]));
            acc = __builtin_amdgcn_mfma_f32_16x16x32_bf16(bk, aq[ks], acc, 0, 0, 0);
          }
          const int kg0 = kb + ct * 16 + lg * 4;
          #pragma unroll
          for (int r = 0; r < 4; ++r) {
            float e = __builtin_amdgcn_exp2f(acc[r] * KC);
            rsum += (kg0 + r <= qg) ? e : 0.f;
          }
        }
        __syncthreads();
        cur ^= 1;
      }
    }
    // stage phase-2 tile 0 while reducing
    stage8k(Ki, Ks[0], w, l);
    stage8k(Vi, Vs[0], w, l);
    rsum += __shfl_xor(rsum, 16);
    rsum += __shfl_xor(rsum, 32);
    const float inv = 1.f / rsum;
    __syncthreads();

    // ================= phase 2: P -> att + O = P·V =================
    f32x4 oacc[4];
    #pragma unroll
    for (int ct = 0; ct < 4; ++ct) oacc[ct] = (f32x4){0.f, 0.f, 0.f, 0.f};

    {
      int cur = 0;
      for (int kt = 0; kt <= qt; ++kt) {
        if (kt < qt) {
          stage8k(Ki + (size_t)(kt + 1) * 4096, Ks[cur ^ 1], w, l);
          stage8k(Vi + (size_t)(kt + 1) * 4096, Vs[cur ^ 1], w, l);
        }
        const us* krb = Ks[cur];
        const us* vrb = Vs[cur];
        const int kb = kt * QT;

        // QK^T (swapped) -> normalized bf16 P into own-wave Ps
        #pragma unroll
        for (int ct = 0; ct < 4; ++ct) {
          f32x4 acc = {0.f, 0.f, 0.f, 0.f};
          #pragma unroll
          for (int ks = 0; ks < 2; ++ks) {
            const int kr = ct * 16 + l16;
            const int d0 = ks * 32 + lg * 8;
            const int idx = (kr * 64 + d0) ^ ((kr & 7) << 3);
            bf16x8 bk = __builtin_bit_cast(bf16x8, *(const u16x8*)(&krb[idx]));
            acc = __builtin_amdgcn_mfma_f32_16x16x32_bf16(bk, aq[ks], acc, 0, 0, 0);
          }
          const int kg0 = kb + ct * 16 + lg * 4;
          u16x4 pb;
          #pragma unroll
          for (int r = 0; r < 4; ++r) {
            float e = __builtin_amdgcn_exp2f(acc[r] * KC) * inv;
            pb[r] = f2bf((kg0 + r <= qg) ? e : 0.f);
          }
          const int pidx = (l16 * 64 + ct * 16 + lg * 4) ^ ((l16 & 7) << 3);
          *(u16x4*)(&Ps[w][pidx]) = pb;
        }

        // att copy: own-wave rows, 256B/row contiguous, nontemporal
        #pragma unroll
        for (int j = 0; j < 4; ++j) {
          const int rloc = lg + 4 * j;
          const int idx = (rloc * 64 + 4 * l16) ^ ((rloc & 7) << 3);
          u16x4 p4 = *(const u16x4*)(&Ps[w][idx]);
          f32x4 pv = { bf2f(p4[0]), bf2f(p4[1]), bf2f(p4[2]), bf2f(p4[3]) };
          __builtin_nontemporal_store(pv,
              (f32x4*)(att + (size_t)(qbase + w * 16 + rloc) * SEQ + kb + 4 * l16));
        }

        // PV (swapped): A = V^T via b128 (same pattern as K reads), B = P^T strip
        bf16x8 pa[2];
        #pragma unroll
        for (int ks = 0; ks < 2; ++ks) {
          const int pidx = (l16 * 64 + ks * 32 + lg * 8) ^ ((l16 & 7) << 3);
          pa[ks] = __builtin_bit_cast(bf16x8, *(const u16x8*)(&Ps[w][pidx]));
        }
        #pragma unroll
        for (int ct = 0; ct < 4; ++ct) {
          #pragma unroll
          for (int ks = 0; ks < 2; ++ks) {
            const int dr = ct * 16 + l16;
            const int key0 = ks * 32 + lg * 8;
            const int vidx = (dr * 64 + key0) ^ ((dr & 7) << 3);
            bf16x8 av = __builtin_bit_cast(bf16x8, *(const u16x8*)(&vrb[vidx]));
            oacc[ct] = __builtin_amdgcn_mfma_f32_16x16x32_bf16(av, pa[ks], oacc[ct], 0, 0, 0);
          }
        }

        __syncthreads();
        cur ^= 1;
      }
    }

    // ---- context write: O^T[d][q], lane q=l16, d = ct*16+lg*4+r ----
    #pragma unroll
    for (int ct = 0; ct < 4; ++ct)
      __builtin_nontemporal_store(oacc[ct],
          (f32x4*)(ctx + (size_t)qg * HD + ct * 16 + lg * 4));
  }
}

// ======================= fallback (R6, proven 153us) =======================
__launch_bounds__(256, 2)
__global__ void attn_fallback(const float* __restrict__ Qg,
                              const float* __restrict__ Kg,
                              const float* __restrict__ Vg,
                              float* __restrict__ out) {
  const int fb = blockIdx.x;
  const int bh = fb & (NHEADS - 1);
  const int pi = fb >> 5;
  const int t  = threadIdx.x;
  const int l  = t & 63;
  const int w  = t >> 6;
  const int l16 = l & 15;
  const int lg  = l >> 4;

  __shared__ __align__(16) us Qs[QT * HD];
  __shared__ __align__(16) us Ks[QT * HD];
  __shared__ __align__(16) us Vs[QT * HD];
  __shared__ __align__(16) us Ps[4][16 * QT];

  const size_t hoff = (size_t)bh * SEQ * HD;
  const float* Qh = Qg + hoff;
  const float* Kh = Kg + hoff;
  const float* Vh = Vg + hoff;
  float* ctx = out + hoff;
  float* att = out + (size_t)NHEADS * SEQ * HD + (size_t)bh * SEQ * SEQ;

  auto load_tile = [&](const float* src, f32x4 (&reg)[4]) {
    #pragma unroll
    for (int j = 0; j < 4; ++j) {
      const int f = t + 256 * j;
      reg[j] = *(const f32x4*)(src + (size_t)(f >> 4) * HD + 4 * (f & 15));
    }
  };
  auto write_k = [&](const f32x4 (&reg)[4], us* dst) {
    #pragma unroll
    for (int j = 0; j < 4; ++j) {
      const int f = t + 256 * j;
      const int r = f >> 4, c4 = f & 15;
      const int idx = (r * 64 + 4 * c4) ^ ((r & 7) << 3);
      u16x4 b = { f2bf(reg[j].x), f2bf(reg[j].y), f2bf(reg[j].z), f2bf(reg[j].w) };
      *(u16x4*)(&dst[idx]) = b;
    }
  };
  auto write_vv = [&](const f32x4 (&reg)[4], us* dst) {
    #pragma unroll
    for (int j = 0; j < 4; ++j) {
      const int f = t + 256 * j;
      const int r = f >> 4, c4 = f & 15;
      const int idx = (r * 64 + 4 * c4) ^ (((r >> 3) & 3) << 4);
      u16x4 b = { f2bf(reg[j].x), f2bf(reg[j].y), f2bf(reg[j].z), f2bf(reg[j].w) };
      *(u16x4*)(&dst[idx]) = b;
    }
  };

  const float sc = 0.125f;

  for (int half = 0; half < 2; ++half) {
    const int qt = half ? (NT - 1 - pi) : pi;
    const int qbase = qt * QT;
    const int qg = qbase + w * 16 + l16;

    __syncthreads();
    {
      const int zc0 = (qt + 1) * QT;
      const int nz4 = (SEQ - zc0) >> 2;
      for (int r = 0; r < QT; ++r) {
        float* rowp = att + (size_t)(qbase + r) * SEQ + zc0;
        for (int c = t; c < nz4; c += 256)
          __builtin_nontemporal_store((f32x4){0.f, 0.f, 0.f, 0.f}, (f32x4*)(rowp + 4 * c));
      }
    }
    {
      f32x4 qreg[4];
      load_tile(Qh + (size_t)qbase * HD, qreg);
      write_k(qreg, Qs);
    }
    __syncthreads();

    bf16x8 aq[2];
    #pragma unroll
    for (int ks = 0; ks < 2; ++ks) {
      const int qr = w * 16 + l16;
      const int d0 = ks * 32 + lg * 8;
      const int idx = (qr * 64 + d0) ^ ((qr & 7) << 3);
      aq[ks] = __builtin_bit_cast(bf16x8, *(const u16x8*)(&Qs[idx]));
    }

    float rsum = 0.f;
    {
      f32x4 kreg[4];
      load_tile(Kh, kreg);
      write_k(kreg, Ks);
      __syncthreads();
      for (int kt = 0; kt <= qt; ++kt) {
        if (kt < qt) load_tile(Kh + (size_t)(kt + 1) * QT * HD, kreg);
        const int kb = kt * QT;
        #pragma unroll
        for (int ct = 0; ct < 4; ++ct) {
          f32x4 acc = {0.f, 0.f, 0.f, 0.f};
          #pragma unroll
          for (int ks = 0; ks < 2; ++ks) {
            const int kr = ct * 16 + l16;
            const int d0 = ks * 32 + lg * 8;
            const int idx = (kr * 64 + d0) ^ ((kr & 7) << 3);
            bf16x8 bk = __builtin_bit_cast(bf16x8, *(const u16x8*)(&Ks[idx]));
            acc = __builtin_amdgcn_mfma_f32_16x16x32_bf16(bk, aq[ks], acc, 0, 0, 0);
          }
          const int kg0 = kb + ct * 16 + lg * 4;
          #pragma unroll
          for (int r = 0; r < 4; ++r) {
            float e = __expf(acc[r] * sc);
            rsum += (kg0 + r <= qg) ? e : 0.f;
          }
        }
        __syncthreads();
        if (kt < qt) write_k(kreg, Ks);
        __syncthreads();
      }
    }
    rsum += __shfl_xor(rsum, 16);
    rsum += __shfl_xor(rsum, 32);
    const float inv = 1.f / rsum;

    f32x4 oacc[4];
    #pragma unroll
    for (int ct = 0; ct < 4; ++ct) oacc[ct] = (f32x4){0.f, 0.f, 0.f, 0.f};

    {
      f32x4 kreg[4], vreg[4];
      load_tile(Kh, kreg);
      load_tile(Vh, vreg);
      write_k(kreg, Ks);
      write_vv(vreg, Vs);
      __syncthreads();
      for (int kt = 0; kt <= qt; ++kt) {
        if (kt < qt) {
          load_tile(Kh + (size_t)(kt + 1) * QT * HD, kreg);
          load_tile(Vh + (size_t)(kt + 1) * QT * HD, vreg);
        }
        const int kb = kt * QT;
        #pragma unroll
        for (int ct = 0; ct < 4; ++ct) {
          f32x4 acc = {0.f, 0.f, 0.f, 0.f};
          #pragma unroll
          for (int ks = 0; ks < 2; ++ks) {
            const int kr = ct * 16 + l16;
            const int d0 = ks * 32 + lg * 8;
            const int idx = (kr * 64 + d0) ^ ((kr & 7) << 3);
            bf16x8 bk = __builtin_bit_cast(bf16x8, *(const u16x8*)(&Ks[idx]));
            acc = __builtin_amdgcn_mfma_f32_16x16x32_bf16(bk, aq[ks], acc, 0, 0, 0);
          }
          const int kg0 = kb + ct * 16 + lg * 4;
          u16x4 pb;
          #pragma unroll
          for (int r = 0; r < 4; ++r) {
            float e = __expf(acc[r] * sc) * inv;
            pb[r] = f2bf((kg0 + r <= qg) ? e : 0.f);
          }
          const int pidx = (l16 * 64 + ct * 16 + lg * 4) ^ ((l16 & 7) << 3);
          *(u16x4*)(&Ps[w][pidx]) = pb;
        }
        #pragma unroll
        for (int ct = 0; ct < 4; ++ct) {
          #pragma unroll
          for (int ks = 0; ks < 2; ++ks) {
            const int key0 = ks * 32 + lg * 8;
            const int pidx = (l16 * 64 + key0) ^ ((l16 & 7) << 3);
            bf16x8 pa = __builtin_bit_cast(bf16x8, *(const u16x8*)(&Ps[w][pidx]));
            bf16x8 av;
            const int dcol = ct * 16 + l16;
            const int xorv = ((key0 >> 3) & 3) << 4;
            #pragma unroll
            for (int j = 0; j < 8; ++j)
              av[j] = __builtin_bit_cast(__bf16, Vs[((key0 + j) * 64 + dcol) ^ xorv]);
            oacc[ct] = __builtin_amdgcn_mfma_f32_16x16x32_bf16(av, pa, oacc[ct], 0, 0, 0);
          }
        }
        __syncthreads();
        #pragma unroll
        for (int j = 0; j < 4; ++j) {
          const int f = t + 256 * j;
          const int r = f >> 4, c4 = f & 15;
          const int ww = r >> 4, qr = r & 15;
          const int idx = (qr * 64 + 4 * c4) ^ ((qr & 7) << 3);
          u16x4 pb = *(const u16x4*)(&Ps[ww][idx]);
          f32x4 pv = { bf2f(pb[0]), bf2f(pb[1]), bf2f(pb[2]), bf2f(pb[3]) };
          __builtin_nontemporal_store(pv,
              (f32x4*)(att + (size_t)(qbase + r) * SEQ + kb + 4 * c4));
        }
        if (kt < qt) {
          write_k(kreg, Ks);
          write_vv(vreg, Vs);
        }
        __syncthreads();
      }
    }
    #pragma unroll
    for (int ct = 0; ct < 4; ++ct)
      *(f32x4*)(ctx + (size_t)qg * HD + ct * 16 + lg * 4) = oacc[ct];
  }
}

extern "C" void kernel_launch(void* const* d_in, const int* in_sizes, int n_in,
                              void* d_out, int out_size, void* d_ws, size_t ws_size,
                              hipStream_t stream) {
  const float* Q = (const float*)d_in[0];
  const float* K = (const float*)d_in[1];
  const float* V = (const float*)d_in[2];
  float* out = (float*)d_out;
  const size_t NEED = (size_t)3 * NHEADS * NT * 4096 * sizeof(us);  // 25.2 MB
  if (ws_size >= NEED && d_ws != nullptr) {
    us* wsp = (us*)d_ws;
    prep_kernel<<<dim3(NHEADS * NT), dim3(256), 0, stream>>>(Q, K, V, wsp);
    attn_main<<<dim3(NT / 2 * NHEADS), dim3(256), 0, stream>>>(wsp, out);
  } else {
    attn_fallback<<<dim3(NT / 2 * NHEADS), dim3(256), 0, stream>>>(Q, K, V, out);
  }
}